// Round 3
// baseline (1037.383 us; speedup 1.0000x reference)
//
#include <hip/hip_runtime.h>

// Problem constants (fixed by reference)
#define HH   480
#define WW   640
#define HWP  (HH*WW)      // 307200
#define NSEM 12
#define NINS 16
#define NCH  28           // sem channels then ins channels

typedef _Float16 f16_t;

union P32  { f16_t h[32]; int4 v[4]; };      // one pixel's channels-last record
union I4H8 { int4 v; f16_t h[8]; };
union I2H4 { int2 v; f16_t h[4]; };
union H4I2 { f16_t h[4]; int2 v; };

// 13-tap Gaussian (sigma=3, r=6)
__device__ __forceinline__ void gauss13(float k[13]) {
    float s = 0.f;
#pragma unroll
    for (int j = 0; j < 13; ++j) {
        float xx = (float)(j - 6);
        float v  = __expf(-(xx * xx) * (1.f / 18.f));
        k[j] = v; s += v;
    }
    float inv = 1.f / s;
#pragma unroll
    for (int j = 0; j < 13; ++j) k[j] *= inv;
}

template <int N>
__device__ __forceinline__ void softmaxN(const float* __restrict__ in, float* __restrict__ out) {
    float m = in[0];
#pragma unroll
    for (int i = 1; i < N; ++i) m = fmaxf(m, in[i]);
    float s = 0.f;
#pragma unroll
    for (int i = 0; i < N; ++i) { float e = __expf(in[i] - m); out[i] = e; s += e; }
    float inv = 1.f / s;
#pragma unroll
    for (int i = 0; i < N; ++i) out[i] *= inv;
}

// ---------------------------------------------------------------------------
// Init: softmax(logits) -> qcl (channels-last f16) + qpm (plane f16),
// plus channels-last f16 logits records (lcl). Same f16 values as before,
// just record layout -> 4 vector stores instead of 28 scalar stores.
// ---------------------------------------------------------------------------
__global__ __launch_bounds__(256) void init_kernel(const float* __restrict__ semL,
                                                   const float* __restrict__ insL,
                                                   int4* __restrict__ qcl4,
                                                   f16_t* __restrict__ qpm,
                                                   int4* __restrict__ lcl4) {
    int p = blockIdx.x * 256 + threadIdx.x;
    float v[NINS], o[NINS];
    P32 pk, lk;
#pragma unroll
    for (int i = 0; i < 32; ++i) { pk.h[i] = (f16_t)0.f; lk.h[i] = (f16_t)0.f; }
#pragma unroll
    for (int i = 0; i < NSEM; ++i) { v[i] = semL[i * HWP + p]; lk.h[i] = (f16_t)v[i]; }
    softmaxN<NSEM>(v, o);
#pragma unroll
    for (int i = 0; i < NSEM; ++i) { f16_t h = (f16_t)o[i]; pk.h[i] = h; qpm[i * HWP + p] = h; }
#pragma unroll
    for (int i = 0; i < NINS; ++i) { v[i] = insL[i * HWP + p]; lk.h[NSEM + i] = (f16_t)v[i]; }
    softmaxN<NINS>(v, o);
#pragma unroll
    for (int i = 0; i < NINS; ++i) { f16_t h = (f16_t)o[i]; pk.h[NSEM + i] = h; qpm[(NSEM + i) * HWP + p] = h; }
#pragma unroll
    for (int j = 0; j < 4; ++j) { qcl4[p * 4 + j] = pk.v[j]; lcl4[p * 4 + j] = lk.v[j]; }
}

// ---------------------------------------------------------------------------
// Fused separable 13x13 blur (zero pad), LDS-tiled 64x32, f16 in/out.
// EXACT round-0 version (f32 LDS) — the f16-LDS variant regressed (bank
// conflicts: 128-B hbh row stride -> 4-way conflicts on all v-pass reads).
// ---------------------------------------------------------------------------
#define BTW 64
#define BTH 32
#define RAWW 80                    // halo 8 left/right, 16-B aligned rows
#define RAWH 44                    // halo 6 top/bottom
__global__ __launch_bounds__(256) void blur_fused_kernel(const f16_t* __restrict__ in,
                                                         f16_t* __restrict__ out) {
    __shared__ float raw[RAWH * RAWW];   // 14080 B
    __shared__ float hb[RAWH * BTW];     // 11264 B
    const int t  = threadIdx.x;
    const int x0 = blockIdx.x * BTW;
    const int y0 = blockIdx.y * BTH;
    const int c  = blockIdx.z;
    const f16_t* __restrict__ plane = in + (size_t)c * HWP;

    float k[13]; gauss13(k);

    // stage: 44 rows x 10 groups of 8 px; groups fully in- or out-of-bounds
    for (int idx = t; idx < RAWH * 10; idx += 256) {
        int row = idx / 10, g = idx - row * 10;
        int gy = y0 - 6 + row;
        int gx8 = x0 - 8 + g * 8;
        float4 lo = {0.f,0.f,0.f,0.f}, hi = {0.f,0.f,0.f,0.f};
        if (gy >= 0 && gy < HH && gx8 >= 0 && gx8 <= WW - 8) {
            I4H8 u; u.v = *(const int4*)&plane[gy * WW + gx8];
            lo.x = (float)u.h[0]; lo.y = (float)u.h[1]; lo.z = (float)u.h[2]; lo.w = (float)u.h[3];
            hi.x = (float)u.h[4]; hi.y = (float)u.h[5]; hi.z = (float)u.h[6]; hi.w = (float)u.h[7];
        }
        *(float4*)&raw[row * RAWW + g * 8]     = lo;
        *(float4*)&raw[row * RAWW + g * 8 + 4] = hi;
    }
    __syncthreads();

    // h-pass: 44 rows x 16 groups of 4 outputs; read 20 floats (5xb128)
    for (int idx = t; idx < RAWH * 16; idx += 256) {
        int row = idx >> 4, xg = idx & 15;
        const float* rp = &raw[row * RAWW + xg * 4];
        float f[20];
#pragma unroll
        for (int q4 = 0; q4 < 5; ++q4) {
            float4 v = *(const float4*)&rp[q4 * 4];
            f[q4*4+0]=v.x; f[q4*4+1]=v.y; f[q4*4+2]=v.z; f[q4*4+3]=v.w;
        }
        float4 o;
        float* op = &o.x;
#pragma unroll
        for (int j = 0; j < 4; ++j) {
            float a = 0.f;
#pragma unroll
            for (int i = 0; i < 13; ++i) a = fmaf(k[i], f[j + 2 + i], a);
            op[j] = a;
        }
        *(float4*)&hb[row * BTW + xg * 4] = o;
    }
    __syncthreads();

    // v-pass: each thread does 4 cols x 2 rows; 14 b128 reads, 2 dwordx2 stores
    {
        const int xg = t & 15;          // 16 col-groups of 4
        const int yg = t >> 4;          // 16 row-groups of 2
        float4 r[14];
#pragma unroll
        for (int i = 0; i < 14; ++i)
            r[i] = *(const float4*)&hb[(yg * 2 + i) * BTW + xg * 4];
#pragma unroll
        for (int j = 0; j < 2; ++j) {
            float a0 = 0.f, a1 = 0.f, a2 = 0.f, a3 = 0.f;
#pragma unroll
            for (int i = 0; i < 13; ++i) {
                float4 v = r[j + i];
                a0 = fmaf(k[i], v.x, a0); a1 = fmaf(k[i], v.y, a1);
                a2 = fmaf(k[i], v.z, a2); a3 = fmaf(k[i], v.w, a3);
            }
            H4I2 s;
            s.h[0] = (f16_t)a0; s.h[1] = (f16_t)a1; s.h[2] = (f16_t)a2; s.h[3] = (f16_t)a3;
            *(int2*)&out[(size_t)c * HWP + (y0 + yg * 2 + j) * WW + (x0 + xg * 4)] = s.v;
        }
    }
}

// ---------------------------------------------------------------------------
// Iteration tail. EXACT round-0 structure (wnr pass, (256,5), sp loads in
// pointwise section). ONE change: logits read as 4 vector loads from lcl
// records, issued right after the barrier (~2000 cyc before use) instead of
// 28 scalar plane loads at the very end.
// ---------------------------------------------------------------------------
#define TTW 32
#define TTH 8
#define TWW (TTW + 4)         // 36
#define TWH (TTH + 4)         // 12
#define TWN (TWW * TWH)       // 432

template <bool LAST>
__global__ __launch_bounds__(256, 5) void tail_kernel(const int4* __restrict__ qcl4,
                                                      const f16_t* __restrict__ sp,
                                                      const float* __restrict__ img,
                                                      const int4* __restrict__ lcl4,
                                                      const float* __restrict__ sem_sw,
                                                      const float* __restrict__ sem_bw,
                                                      const float* __restrict__ sem_compat,
                                                      const float* __restrict__ ins_sw,
                                                      const float* __restrict__ ins_bw,
                                                      const int*   __restrict__ labels,
                                                      const float* __restrict__ cross_is,
                                                      const float* __restrict__ cross_si,
                                                      int4* __restrict__ qclo4,
                                                      f16_t* __restrict__ qpmo,
                                                      float* __restrict__ dout) {
    __shared__ int4  lqA[TWN * 3];       // 20736 B (channels 0..23)
    __shared__ int2  lqB[TWN];           //  3456 B (channels 24..27)
    __shared__ float limg[3 * TWN];      //  5184 B
    __shared__ float sC[NSEM * NSEM];
    __shared__ float sMis[NINS * NSEM];
    __shared__ float sMsi[NINS * NSEM];
    __shared__ float sws[NSEM], sbs[NSEM], swi[NINS], sbi[NINS];

    const int t  = threadIdx.x;
    const int tx = t & 31;
    const int ty = t >> 5;
    const int x0 = blockIdx.x * TTW;
    const int y0 = blockIdx.y * TTH;
    const int p  = (y0 + ty) * WW + (x0 + tx);

    if (t < NSEM * NSEM) sC[t] = sem_compat[t];
    if (t < NINS * NSEM) {
        int i = t / NSEM, o = t - i * NSEM;
        sMis[t] = cross_is[labels[i] * NSEM + o];
        sMsi[t] = cross_si[labels[i] * NSEM + o];  // [o_ins*12 + i_sem]
    }
    if (t < NSEM) { sws[t] = sem_sw[t]; sbs[t] = sem_bw[t]; }
    if (t < NINS) { int l = labels[t]; swi[t] = ins_sw[l]; sbi[t] = ins_bw[l]; }

    // stage q window, A-part: idx = e*3+s  (TWN*3 = 1296)
#pragma unroll
    for (int j = 0; j < 6; ++j) {
        int idx = t + j * 256;
        if (idx < TWN * 3) {
            int e = idx / 3, s = idx - e * 3;
            int ly = e / TWW, lx = e - ly * TWW;
            int gy = min(max(y0 - 2 + ly, 0), HH - 1);
            int gx = min(max(x0 - 2 + lx, 0), WW - 1);
            lqA[idx] = qcl4[(gy * WW + gx) * 4 + s];
        }
    }
    // B-part: channels 24..27 = int2 #6 of the 64-B record
#pragma unroll
    for (int j = 0; j < 2; ++j) {
        int e = t + j * 256;
        if (e < TWN) {
            int ly = e / TWW, lx = e - ly * TWW;
            int gy = min(max(y0 - 2 + ly, 0), HH - 1);
            int gx = min(max(x0 - 2 + lx, 0), WW - 1);
            lqB[e] = ((const int2*)qcl4)[(gy * WW + gx) * 8 + 6];
        }
    }
    // image window (fp32, edge-clamped)
    for (int idx = t; idx < 3 * TWN; idx += 256) {
        int cc  = idx / TWN;
        int rem = idx - cc * TWN;
        int ly  = rem / TWW, lx = rem - ly * TWW;
        int gy  = min(max(y0 - 2 + ly, 0), HH - 1);
        int gx  = min(max(x0 - 2 + lx, 0), WW - 1);
        limg[idx] = img[(size_t)cc * HWP + gy * WW + gx];
    }
    __syncthreads();

    // own-pixel logits record: 4 vector loads, consumed ~2000 cycles later
    // in the pointwise tail -> latency fully hidden under weights + gather.
    I4H8 l0, l1, l2; I2H4 l3;
    l0.v = lcl4[p * 4 + 0];
    l1.v = lcl4[p * 4 + 1];
    l2.v = lcl4[p * 4 + 2];
    l3.v = ((const int2*)lcl4)[p * 8 + 6];

    // per-pixel bilateral weights from staged image window
    float wnr[25];
    {
        const int wc = (ty + 2) * TWW + (tx + 2);
        float i0 = limg[wc], i1 = limg[TWN + wc], i2 = limg[2 * TWN + wc];
        float den = 0.f;
        int d = 0;
#pragma unroll
        for (int dy = 0; dy < 5; ++dy) {
#pragma unroll
            for (int dx = 0; dx < 5; ++dx) {
                int nb = (ty + dy) * TWW + (tx + dx);
                float d0 = limg[nb] - i0;
                float d1 = limg[TWN + nb] - i1;
                float d2 = limg[2 * TWN + nb] - i2;
                float cd = d0 * d0 + d1 * d1 + d2 * d2;
                float sd = (float)((dy - 2) * (dy - 2) + (dx - 2) * (dx - 2));
                float wv = __expf(-sd * (1.f / 18.f) - cd * (1.f / 0.045f));
                wnr[d++] = wv; den += wv;
            }
        }
        float inv = 1.f / den;
#pragma unroll
        for (int j = 0; j < 25; ++j) wnr[j] *= inv;
    }

    // bilateral gather: 25 taps x (3 b128 + 1 b64)
    float bl[NCH];
#pragma unroll
    for (int c = 0; c < NCH; ++c) bl[c] = 0.f;
#pragma unroll
    for (int dy = 0; dy < 5; ++dy) {
        int rb = (ty + dy) * TWW + tx;
#pragma unroll
        for (int dx = 0; dx < 5; ++dx) {
            float w = wnr[dy * 5 + dx];
            int e = rb + dx;
#pragma unroll
            for (int s = 0; s < 3; ++s) {
                I4H8 u; u.v = lqA[e * 3 + s];
#pragma unroll
                for (int i = 0; i < 8; ++i)
                    bl[s * 8 + i] = fmaf((float)u.h[i], w, bl[s * 8 + i]);
            }
            I2H4 ub; ub.v = lqB[e];
#pragma unroll
            for (int i = 0; i < 4; ++i)
                bl[24 + i] = fmaf((float)ub.h[i], w, bl[24 + i]);
        }
    }

    // pointwise tail (sp f16 planes, logits from lcl registers)
    float comb[NSEM];
#pragma unroll
    for (int i = 0; i < NSEM; ++i)
        comb[i] = sws[i] * (float)sp[i * HWP + p] + sbs[i] * bl[i];
    float ts[NSEM];
#pragma unroll
    for (int o = 0; o < NSEM; ++o) {
        float a = (o < 8) ? (float)l0.h[o] : (float)l1.h[o - 8];
#pragma unroll
        for (int i = 0; i < NSEM; ++i) a = fmaf(sC[i * NSEM + o], comb[i], a);
        ts[o] = a;
    }
    float ti[NINS];
#pragma unroll
    for (int i = 0; i < NINS; ++i) {
        const int c = NSEM + i;   // 12..27
        float lg = (c < 16) ? (float)l1.h[c - 8]
                 : (c < 24) ? (float)l2.h[c - 16]
                            : (float)l3.h[c - 24];
        ti[i] = lg + swi[i] * (float)sp[c * HWP + p] + sbi[i] * bl[c];
    }

    float sIns[NINS], sSem[NSEM];
    softmaxN<NINS>(ti, sIns);
    softmaxN<NSEM>(ts, sSem);

    float nts[NSEM];
#pragma unroll
    for (int o = 0; o < NSEM; ++o) {
        float a = ts[o];
#pragma unroll
        for (int i = 0; i < NINS; ++i) a = fmaf(sMis[i * NSEM + o], sIns[i], a);
        nts[o] = a;
    }
    float nti[NINS];
#pragma unroll
    for (int o = 0; o < NINS; ++o) {
        float a = ti[o];
#pragma unroll
        for (int i = 0; i < NSEM; ++i) a = fmaf(sMsi[o * NSEM + i], sSem[i], a);
        nti[o] = a;
    }

    float oq1[NSEM], oq2[NINS];
    softmaxN<NSEM>(nts, oq1);
    softmaxN<NINS>(nti, oq2);

    if (LAST) {
#pragma unroll
        for (int i = 0; i < NSEM; ++i) dout[i * HWP + p] = oq1[i];
#pragma unroll
        for (int i = 0; i < NINS; ++i) dout[(NSEM + i) * HWP + p] = oq2[i];
    } else {
        P32 pk;
#pragma unroll
        for (int i = 0; i < 32; ++i) pk.h[i] = (f16_t)0.f;
#pragma unroll
        for (int i = 0; i < NSEM; ++i) { f16_t h = (f16_t)oq1[i]; pk.h[i] = h; qpmo[i * HWP + p] = h; }
#pragma unroll
        for (int i = 0; i < NINS; ++i) { f16_t h = (f16_t)oq2[i]; pk.h[NSEM + i] = h; qpmo[(NSEM + i) * HWP + p] = h; }
#pragma unroll
        for (int j = 0; j < 4; ++j) qclo4[p * 4 + j] = pk.v[j];
    }
}

// ---------------------------------------------------------------------------
extern "C" void kernel_launch(void* const* d_in, const int* in_sizes, int n_in,
                              void* d_out, int out_size, void* d_ws, size_t ws_size,
                              hipStream_t stream) {
    const float* image      = (const float*)d_in[0];
    const float* semL       = (const float*)d_in[1];
    const float* insL       = (const float*)d_in[2];
    const int*   labels     = (const int*)  d_in[3];
    const float* sem_sw     = (const float*)d_in[4];
    const float* sem_bw     = (const float*)d_in[5];
    const float* sem_compat = (const float*)d_in[6];
    const float* ins_sw     = (const float*)d_in[7];
    const float* ins_bw     = (const float*)d_in[8];
    const float* cross_is   = (const float*)d_in[9];
    const float* cross_si   = (const float*)d_in[10];

    // Workspace: qclA | qclB | qpmA | qpmB | sp | lcl
    char* ws = (char*)d_ws;
    int4*  qclA  = (int4*)ws;                                   ws += (size_t)HWP * 64;
    int4*  qclB  = (int4*)ws;                                   ws += (size_t)HWP * 64;
    f16_t* qpmA  = (f16_t*)ws;                                  ws += (size_t)NCH * HWP * 2;
    f16_t* qpmB  = (f16_t*)ws;                                  ws += (size_t)NCH * HWP * 2;
    f16_t* sp    = (f16_t*)ws;                                  ws += (size_t)NCH * HWP * 2;
    int4*  lcl   = (int4*)ws;

    const int PIX_BLOCKS = HWP / 256;  // 1200
    init_kernel<<<PIX_BLOCKS, 256, 0, stream>>>(semL, insL, qclA, qpmA, lcl);

    dim3 bgrid(WW / BTW, HH / BTH, NCH);    // 10 x 15 x 28
    dim3 tgrid(WW / TTW, HH / TTH);         // 20 x 60

    // iter 0: A -> B
    blur_fused_kernel<<<bgrid, 256, 0, stream>>>(qpmA, sp);
    tail_kernel<false><<<tgrid, 256, 0, stream>>>(qclA, sp, image, lcl,
                                                  sem_sw, sem_bw, sem_compat,
                                                  ins_sw, ins_bw, labels,
                                                  cross_is, cross_si, qclB, qpmB, nullptr);
    // iter 1: B -> A
    blur_fused_kernel<<<bgrid, 256, 0, stream>>>(qpmB, sp);
    tail_kernel<false><<<tgrid, 256, 0, stream>>>(qclB, sp, image, lcl,
                                                  sem_sw, sem_bw, sem_compat,
                                                  ins_sw, ins_bw, labels,
                                                  cross_is, cross_si, qclA, qpmA, nullptr);
    // iter 2: A -> d_out (fp32 plane-major)
    blur_fused_kernel<<<bgrid, 256, 0, stream>>>(qpmA, sp);
    tail_kernel<true><<<tgrid, 256, 0, stream>>>(qclA, sp, image, lcl,
                                                 sem_sw, sem_bw, sem_compat,
                                                 ins_sw, ins_bw, labels,
                                                 cross_is, cross_si, nullptr, nullptr, (float*)d_out);
}

// Round 4
// 280.815 us; speedup vs baseline: 3.6942x; 3.6942x over previous
//
#include <hip/hip_runtime.h>

// Problem constants (fixed by reference)
#define HH   480
#define WW   640
#define HWP  (HH*WW)      // 307200
#define NSEM 12
#define NINS 16
#define NCH  28           // sem channels then ins channels

typedef _Float16 f16_t;

union P32 { f16_t h[32]; int4 v[4]; };      // one pixel's channels-last record
union I4H8 { int4 v; f16_t h[8]; };
union I2H4 { int2 v; f16_t h[4]; };
union H4I2 { f16_t h[4]; int2 v; };

// 13-tap Gaussian (sigma=3, r=6)
__device__ __forceinline__ void gauss13(float k[13]) {
    float s = 0.f;
#pragma unroll
    for (int j = 0; j < 13; ++j) {
        float xx = (float)(j - 6);
        float v  = __expf(-(xx * xx) * (1.f / 18.f));
        k[j] = v; s += v;
    }
    float inv = 1.f / s;
#pragma unroll
    for (int j = 0; j < 13; ++j) k[j] *= inv;
}

template <int N>
__device__ __forceinline__ void softmaxN(const float* __restrict__ in, float* __restrict__ out) {
    float m = in[0];
#pragma unroll
    for (int i = 1; i < N; ++i) m = fmaxf(m, in[i]);
    float s = 0.f;
#pragma unroll
    for (int i = 0; i < N; ++i) { float e = __expf(in[i] - m); out[i] = e; s += e; }
    float inv = 1.f / s;
#pragma unroll
    for (int i = 0; i < N; ++i) out[i] *= inv;
}

// ---------------------------------------------------------------------------
// Init: softmax(logits) -> qcl (channels-last f16) + qpm (plane f16),
// plus f16 copies of the logits (8x finer ulp than bf16 -> ~+3e-3 error only)
// ---------------------------------------------------------------------------
__global__ __launch_bounds__(256) void init_kernel(const float* __restrict__ semL,
                                                   const float* __restrict__ insL,
                                                   int4* __restrict__ qcl4,
                                                   f16_t* __restrict__ qpm,
                                                   f16_t* __restrict__ semLh,
                                                   f16_t* __restrict__ insLh) {
    int p = blockIdx.x * 256 + threadIdx.x;
    float v[NINS], o[NINS];
    P32 pk;
#pragma unroll
    for (int i = 0; i < 32; ++i) pk.h[i] = (f16_t)0.f;
#pragma unroll
    for (int i = 0; i < NSEM; ++i) { v[i] = semL[i * HWP + p]; semLh[i * HWP + p] = (f16_t)v[i]; }
    softmaxN<NSEM>(v, o);
#pragma unroll
    for (int i = 0; i < NSEM; ++i) { f16_t h = (f16_t)o[i]; pk.h[i] = h; qpm[i * HWP + p] = h; }
#pragma unroll
    for (int i = 0; i < NINS; ++i) { v[i] = insL[i * HWP + p]; insLh[i * HWP + p] = (f16_t)v[i]; }
    softmaxN<NINS>(v, o);
#pragma unroll
    for (int i = 0; i < NINS; ++i) { f16_t h = (f16_t)o[i]; pk.h[NSEM + i] = h; qpm[(NSEM + i) * HWP + p] = h; }
#pragma unroll
    for (int j = 0; j < 4; ++j) qcl4[p * 4 + j] = pk.v[j];
}

// ---------------------------------------------------------------------------
// Fused separable 13x13 blur (zero pad), LDS-tiled 64x32, f16 in/out.
// Round-0 structure; ONLY change: v-pass streams its 14 rows and accumulates
// on the fly (8 live acc regs instead of a 56-VGPR r[14] pile). FMA order per
// output is identical to round-0 -> bit-identical numerics.
// ---------------------------------------------------------------------------
#define BTW 64
#define BTH 32
#define RAWW 80                    // halo 8 left/right, 16-B aligned rows
#define RAWH 44                    // halo 6 top/bottom
__global__ __launch_bounds__(256) void blur_fused_kernel(const f16_t* __restrict__ in,
                                                         f16_t* __restrict__ out) {
    __shared__ float raw[RAWH * RAWW];   // 14080 B
    __shared__ float hb[RAWH * BTW];     // 11264 B
    const int t  = threadIdx.x;
    const int x0 = blockIdx.x * BTW;
    const int y0 = blockIdx.y * BTH;
    const int c  = blockIdx.z;
    const f16_t* __restrict__ plane = in + (size_t)c * HWP;

    float k[13]; gauss13(k);

    // stage: 44 rows x 10 groups of 8 px; groups fully in- or out-of-bounds
    for (int idx = t; idx < RAWH * 10; idx += 256) {
        int row = idx / 10, g = idx - row * 10;
        int gy = y0 - 6 + row;
        int gx8 = x0 - 8 + g * 8;
        float4 lo = {0.f,0.f,0.f,0.f}, hi = {0.f,0.f,0.f,0.f};
        if (gy >= 0 && gy < HH && gx8 >= 0 && gx8 <= WW - 8) {
            I4H8 u; u.v = *(const int4*)&plane[gy * WW + gx8];
            lo.x = (float)u.h[0]; lo.y = (float)u.h[1]; lo.z = (float)u.h[2]; lo.w = (float)u.h[3];
            hi.x = (float)u.h[4]; hi.y = (float)u.h[5]; hi.z = (float)u.h[6]; hi.w = (float)u.h[7];
        }
        *(float4*)&raw[row * RAWW + g * 8]     = lo;
        *(float4*)&raw[row * RAWW + g * 8 + 4] = hi;
    }
    __syncthreads();

    // h-pass: 44 rows x 16 groups of 4 outputs; read 20 floats (5xb128)
    for (int idx = t; idx < RAWH * 16; idx += 256) {
        int row = idx >> 4, xg = idx & 15;
        const float* rp = &raw[row * RAWW + xg * 4];
        float f[20];
#pragma unroll
        for (int q4 = 0; q4 < 5; ++q4) {
            float4 v = *(const float4*)&rp[q4 * 4];
            f[q4*4+0]=v.x; f[q4*4+1]=v.y; f[q4*4+2]=v.z; f[q4*4+3]=v.w;
        }
        float4 o;
        float* op = &o.x;
#pragma unroll
        for (int j = 0; j < 4; ++j) {
            float a = 0.f;
#pragma unroll
            for (int i = 0; i < 13; ++i) a = fmaf(k[i], f[j + 2 + i], a);
            op[j] = a;
        }
        *(float4*)&hb[row * BTW + xg * 4] = o;
    }
    __syncthreads();

    // v-pass: each thread does 4 cols x 2 rows; stream 14 b128 reads,
    // accumulating both rows on the fly (low register pressure).
    {
        const int xg = t & 15;          // 16 col-groups of 4
        const int yg = t >> 4;          // 16 row-groups of 2
        float a0 = 0.f, a1 = 0.f, a2 = 0.f, a3 = 0.f;   // output row yg*2
        float b0 = 0.f, b1 = 0.f, b2 = 0.f, b3 = 0.f;   // output row yg*2+1
#pragma unroll
        for (int i = 0; i < 14; ++i) {
            float4 v = *(const float4*)&hb[(yg * 2 + i) * BTW + xg * 4];
            if (i < 13) {
                a0 = fmaf(k[i], v.x, a0); a1 = fmaf(k[i], v.y, a1);
                a2 = fmaf(k[i], v.z, a2); a3 = fmaf(k[i], v.w, a3);
            }
            if (i >= 1) {
                b0 = fmaf(k[i - 1], v.x, b0); b1 = fmaf(k[i - 1], v.y, b1);
                b2 = fmaf(k[i - 1], v.z, b2); b3 = fmaf(k[i - 1], v.w, b3);
            }
        }
        H4I2 s0;
        s0.h[0] = (f16_t)a0; s0.h[1] = (f16_t)a1; s0.h[2] = (f16_t)a2; s0.h[3] = (f16_t)a3;
        *(int2*)&out[(size_t)c * HWP + (y0 + yg * 2) * WW + (x0 + xg * 4)] = s0.v;
        H4I2 s1;
        s1.h[0] = (f16_t)b0; s1.h[1] = (f16_t)b1; s1.h[2] = (f16_t)b2; s1.h[3] = (f16_t)b3;
        *(int2*)&out[(size_t)c * HWP + (y0 + yg * 2 + 1) * WW + (x0 + xg * 4)] = s1.v;
    }
}

// ---------------------------------------------------------------------------
// Iteration tail. EXACT round-0 kernel (proven 42 us) — untouched.
// ---------------------------------------------------------------------------
#define TTW 32
#define TTH 8
#define TWW (TTW + 4)         // 36
#define TWH (TTH + 4)         // 12
#define TWN (TWW * TWH)       // 432

template <bool LAST>
__global__ __launch_bounds__(256, 5) void tail_kernel(const int4* __restrict__ qcl4,
                                                      const f16_t* __restrict__ sp,
                                                      const float* __restrict__ img,
                                                      const f16_t* __restrict__ semLh,
                                                      const f16_t* __restrict__ insLh,
                                                      const float* __restrict__ sem_sw,
                                                      const float* __restrict__ sem_bw,
                                                      const float* __restrict__ sem_compat,
                                                      const float* __restrict__ ins_sw,
                                                      const float* __restrict__ ins_bw,
                                                      const int*   __restrict__ labels,
                                                      const float* __restrict__ cross_is,
                                                      const float* __restrict__ cross_si,
                                                      int4* __restrict__ qclo4,
                                                      f16_t* __restrict__ qpmo,
                                                      float* __restrict__ dout) {
    __shared__ int4  lqA[TWN * 3];       // 20736 B (channels 0..23)
    __shared__ int2  lqB[TWN];           //  3456 B (channels 24..27)
    __shared__ float limg[3 * TWN];      //  5184 B
    __shared__ float sC[NSEM * NSEM];
    __shared__ float sMis[NINS * NSEM];
    __shared__ float sMsi[NINS * NSEM];
    __shared__ float sws[NSEM], sbs[NSEM], swi[NINS], sbi[NINS];

    const int t  = threadIdx.x;
    const int tx = t & 31;
    const int ty = t >> 5;
    const int x0 = blockIdx.x * TTW;
    const int y0 = blockIdx.y * TTH;
    const int p  = (y0 + ty) * WW + (x0 + tx);

    if (t < NSEM * NSEM) sC[t] = sem_compat[t];
    if (t < NINS * NSEM) {
        int i = t / NSEM, o = t - i * NSEM;
        sMis[t] = cross_is[labels[i] * NSEM + o];
        sMsi[t] = cross_si[labels[i] * NSEM + o];  // [o_ins*12 + i_sem]
    }
    if (t < NSEM) { sws[t] = sem_sw[t]; sbs[t] = sem_bw[t]; }
    if (t < NINS) { int l = labels[t]; swi[t] = ins_sw[l]; sbi[t] = ins_bw[l]; }

    // stage q window, A-part: idx = e*3+s  (TWN*3 = 1296)
#pragma unroll
    for (int j = 0; j < 6; ++j) {
        int idx = t + j * 256;
        if (idx < TWN * 3) {
            int e = idx / 3, s = idx - e * 3;
            int ly = e / TWW, lx = e - ly * TWW;
            int gy = min(max(y0 - 2 + ly, 0), HH - 1);
            int gx = min(max(x0 - 2 + lx, 0), WW - 1);
            lqA[idx] = qcl4[(gy * WW + gx) * 4 + s];
        }
    }
    // B-part: channels 24..27 = int2 #6 of the 64-B record
#pragma unroll
    for (int j = 0; j < 2; ++j) {
        int e = t + j * 256;
        if (e < TWN) {
            int ly = e / TWW, lx = e - ly * TWW;
            int gy = min(max(y0 - 2 + ly, 0), HH - 1);
            int gx = min(max(x0 - 2 + lx, 0), WW - 1);
            lqB[e] = ((const int2*)qcl4)[(gy * WW + gx) * 8 + 6];
        }
    }
    // image window (fp32, edge-clamped)
    for (int idx = t; idx < 3 * TWN; idx += 256) {
        int cc  = idx / TWN;
        int rem = idx - cc * TWN;
        int ly  = rem / TWW, lx = rem - ly * TWW;
        int gy  = min(max(y0 - 2 + ly, 0), HH - 1);
        int gx  = min(max(x0 - 2 + lx, 0), WW - 1);
        limg[idx] = img[(size_t)cc * HWP + gy * WW + gx];
    }
    __syncthreads();

    // per-pixel bilateral weights from staged image window
    float wnr[25];
    {
        const int wc = (ty + 2) * TWW + (tx + 2);
        float i0 = limg[wc], i1 = limg[TWN + wc], i2 = limg[2 * TWN + wc];
        float den = 0.f;
        int d = 0;
#pragma unroll
        for (int dy = 0; dy < 5; ++dy) {
#pragma unroll
            for (int dx = 0; dx < 5; ++dx) {
                int nb = (ty + dy) * TWW + (tx + dx);
                float d0 = limg[nb] - i0;
                float d1 = limg[TWN + nb] - i1;
                float d2 = limg[2 * TWN + nb] - i2;
                float cd = d0 * d0 + d1 * d1 + d2 * d2;
                float sd = (float)((dy - 2) * (dy - 2) + (dx - 2) * (dx - 2));
                float wv = __expf(-sd * (1.f / 18.f) - cd * (1.f / 0.045f));
                wnr[d++] = wv; den += wv;
            }
        }
        float inv = 1.f / den;
#pragma unroll
        for (int j = 0; j < 25; ++j) wnr[j] *= inv;
    }

    // bilateral gather: 25 taps x (3 b128 + 1 b64)
    float bl[NCH];
#pragma unroll
    for (int c = 0; c < NCH; ++c) bl[c] = 0.f;
#pragma unroll
    for (int dy = 0; dy < 5; ++dy) {
        int rb = (ty + dy) * TWW + tx;
#pragma unroll
        for (int dx = 0; dx < 5; ++dx) {
            float w = wnr[dy * 5 + dx];
            int e = rb + dx;
#pragma unroll
            for (int s = 0; s < 3; ++s) {
                I4H8 u; u.v = lqA[e * 3 + s];
#pragma unroll
                for (int i = 0; i < 8; ++i)
                    bl[s * 8 + i] = fmaf((float)u.h[i], w, bl[s * 8 + i]);
            }
            I2H4 ub; ub.v = lqB[e];
#pragma unroll
            for (int i = 0; i < 4; ++i)
                bl[24 + i] = fmaf((float)ub.h[i], w, bl[24 + i]);
        }
    }

    // pointwise tail (sp f16, logits f16)
    float comb[NSEM];
#pragma unroll
    for (int i = 0; i < NSEM; ++i)
        comb[i] = sws[i] * (float)sp[i * HWP + p] + sbs[i] * bl[i];
    float ts[NSEM];
#pragma unroll
    for (int o = 0; o < NSEM; ++o) {
        float a = (float)semLh[o * HWP + p];
#pragma unroll
        for (int i = 0; i < NSEM; ++i) a = fmaf(sC[i * NSEM + o], comb[i], a);
        ts[o] = a;
    }
    float ti[NINS];
#pragma unroll
    for (int i = 0; i < NINS; ++i)
        ti[i] = (float)insLh[i * HWP + p] + swi[i] * (float)sp[(NSEM + i) * HWP + p] + sbi[i] * bl[NSEM + i];

    float sIns[NINS], sSem[NSEM];
    softmaxN<NINS>(ti, sIns);
    softmaxN<NSEM>(ts, sSem);

    float nts[NSEM];
#pragma unroll
    for (int o = 0; o < NSEM; ++o) {
        float a = ts[o];
#pragma unroll
        for (int i = 0; i < NINS; ++i) a = fmaf(sMis[i * NSEM + o], sIns[i], a);
        nts[o] = a;
    }
    float nti[NINS];
#pragma unroll
    for (int o = 0; o < NINS; ++o) {
        float a = ti[o];
#pragma unroll
        for (int i = 0; i < NSEM; ++i) a = fmaf(sMsi[o * NSEM + i], sSem[i], a);
        nti[o] = a;
    }

    float oq1[NSEM], oq2[NINS];
    softmaxN<NSEM>(nts, oq1);
    softmaxN<NINS>(nti, oq2);

    if (LAST) {
#pragma unroll
        for (int i = 0; i < NSEM; ++i) dout[i * HWP + p] = oq1[i];
#pragma unroll
        for (int i = 0; i < NINS; ++i) dout[(NSEM + i) * HWP + p] = oq2[i];
    } else {
        P32 pk;
#pragma unroll
        for (int i = 0; i < 32; ++i) pk.h[i] = (f16_t)0.f;
#pragma unroll
        for (int i = 0; i < NSEM; ++i) { f16_t h = (f16_t)oq1[i]; pk.h[i] = h; qpmo[i * HWP + p] = h; }
#pragma unroll
        for (int i = 0; i < NINS; ++i) { f16_t h = (f16_t)oq2[i]; pk.h[NSEM + i] = h; qpmo[(NSEM + i) * HWP + p] = h; }
#pragma unroll
        for (int j = 0; j < 4; ++j) qclo4[p * 4 + j] = pk.v[j];
    }
}

// ---------------------------------------------------------------------------
extern "C" void kernel_launch(void* const* d_in, const int* in_sizes, int n_in,
                              void* d_out, int out_size, void* d_ws, size_t ws_size,
                              hipStream_t stream) {
    const float* image      = (const float*)d_in[0];
    const float* semL       = (const float*)d_in[1];
    const float* insL       = (const float*)d_in[2];
    const int*   labels     = (const int*)  d_in[3];
    const float* sem_sw     = (const float*)d_in[4];
    const float* sem_bw     = (const float*)d_in[5];
    const float* sem_compat = (const float*)d_in[6];
    const float* ins_sw     = (const float*)d_in[7];
    const float* ins_bw     = (const float*)d_in[8];
    const float* cross_is   = (const float*)d_in[9];
    const float* cross_si   = (const float*)d_in[10];

    // Workspace: qclA | qclB | qpmA | qpmB | sp | semLh | insLh
    char* ws = (char*)d_ws;
    int4*  qclA  = (int4*)ws;                                   ws += (size_t)HWP * 64;
    int4*  qclB  = (int4*)ws;                                   ws += (size_t)HWP * 64;
    f16_t* qpmA  = (f16_t*)ws;                                  ws += (size_t)NCH * HWP * 2;
    f16_t* qpmB  = (f16_t*)ws;                                  ws += (size_t)NCH * HWP * 2;
    f16_t* sp    = (f16_t*)ws;                                  ws += (size_t)NCH * HWP * 2;
    f16_t* semLh = (f16_t*)ws;                                  ws += (size_t)NSEM * HWP * 2;
    f16_t* insLh = (f16_t*)ws;

    const int PIX_BLOCKS = HWP / 256;  // 1200
    init_kernel<<<PIX_BLOCKS, 256, 0, stream>>>(semL, insL, qclA, qpmA, semLh, insLh);

    dim3 bgrid(WW / BTW, HH / BTH, NCH);    // 10 x 15 x 28
    dim3 tgrid(WW / TTW, HH / TTH);         // 20 x 60

    // iter 0: A -> B
    blur_fused_kernel<<<bgrid, 256, 0, stream>>>(qpmA, sp);
    tail_kernel<false><<<tgrid, 256, 0, stream>>>(qclA, sp, image, semLh, insLh,
                                                  sem_sw, sem_bw, sem_compat,
                                                  ins_sw, ins_bw, labels,
                                                  cross_is, cross_si, qclB, qpmB, nullptr);
    // iter 1: B -> A
    blur_fused_kernel<<<bgrid, 256, 0, stream>>>(qpmB, sp);
    tail_kernel<false><<<tgrid, 256, 0, stream>>>(qclB, sp, image, semLh, insLh,
                                                  sem_sw, sem_bw, sem_compat,
                                                  ins_sw, ins_bw, labels,
                                                  cross_is, cross_si, qclA, qpmA, nullptr);
    // iter 2: A -> d_out (fp32 plane-major)
    blur_fused_kernel<<<bgrid, 256, 0, stream>>>(qpmA, sp);
    tail_kernel<true><<<tgrid, 256, 0, stream>>>(qclA, sp, image, semLh, insLh,
                                                 sem_sw, sem_bw, sem_compat,
                                                 ins_sw, ins_bw, labels,
                                                 cross_is, cross_si, nullptr, nullptr, (float*)d_out);
}